// Round 6
// baseline (236.515 us; speedup 1.0000x reference)
//
#include <hip/hip_runtime.h>
#include <hip/hip_bf16.h>
#include <math.h>

#define B_  4
#define S_  2048
#define D_  256
#define H_  8
#define HD_ 32
// 1/sqrt(32) * log2(e): folded into Q so softmax is a bare exp2
#define QSCALE 0.25504175929589786f

typedef short  bf16x8 __attribute__((ext_vector_type(8)));
typedef float  f32x4  __attribute__((ext_vector_type(4)));
typedef float  f32x16 __attribute__((ext_vector_type(16)));
typedef unsigned short ushort_t;
typedef unsigned int   uint_t;

__device__ __forceinline__ ushort_t f2b(float f) {
    union { float f; unsigned u; } v; v.f = f;
    unsigned r = (v.u + 0x7FFFu + ((v.u >> 16) & 1u)) >> 16;
    return (ushort_t)r;
}
__device__ __forceinline__ float b2f(ushort_t s) {
    return __uint_as_float((uint_t)s << 16);
}
__device__ __forceinline__ f32x16 zero16() {
    f32x16 z;
#pragma unroll
    for (int i = 0; i < 16; ++i) z[i] = 0.f;
    return z;
}

// ---------------- reductions ----------------
__device__ __forceinline__ float wave_sum(float v) {
#pragma unroll
    for (int o = 32; o > 0; o >>= 1) v += __shfl_down(v, o, 64);
    return v;
}
__device__ __forceinline__ float block_sum256(float v, float* scr) {
    v = wave_sum(v);
    int lane = threadIdx.x & 63, wid = threadIdx.x >> 6;
    if (lane == 0) scr[wid] = v;
    __syncthreads();
    float r = scr[0] + scr[1] + scr[2] + scr[3];
    __syncthreads();
    return r;
}

// ---------------- merged prep: adj->bits | weight cvt+frag-reorder | layernorm ----------------
#define WQ_SZ 196608   // 768*256
#define WS_SZ 65536    // 256*256
#define NB_ADJ 8192    // (4*2048*2048)/256/8  (8 groups per block)
#define NB_WC  2560    // (WQ_SZ+7*WS_SZ)/256
#define NB_LN  8192
__global__ __launch_bounds__(256)
void prep_kernel(const int* __restrict__ adj, uint_t* __restrict__ bits,
                 const float* __restrict__ w0, const float* __restrict__ w1,
                 const float* __restrict__ w2, const float* __restrict__ w3,
                 const float* __restrict__ w4, const float* __restrict__ w5,
                 const float* __restrict__ w6, const float* __restrict__ w7,
                 ushort_t* __restrict__ wout,
                 const float* __restrict__ x, const float* __restrict__ g,
                 const float* __restrict__ bb, ushort_t* __restrict__ xn_b) {
    __shared__ float scr[4];
    int blk = blockIdx.x, tid = threadIdx.x;
    if (blk < NB_ADJ) {
        int lane = tid & 63;
#pragma unroll
        for (int gp = 0; gp < 8; ++gp) {
            size_t i = ((size_t)blk * 8 + gp) * 256 + tid;
            unsigned long long m = __ballot(adj[i] != 0);
            size_t wbase = (((size_t)blk * 8 + gp) * 256 + (tid & ~63)) >> 5;
            if (lane == 0)  bits[wbase]     = (uint_t)m;
            if (lane == 32) bits[wbase + 1] = (uint_t)(m >> 32);
        }
    } else if (blk < NB_ADJ + NB_WC) {
        int idx = (blk - NB_ADJ) * 256 + tid;
        const float* src; int o;
        if (idx < WQ_SZ) { src = w0; o = idx; }
        else {
            int j = idx - WQ_SZ, seg = j >> 16; o = j & (WS_SZ - 1);
            src = (seg == 0) ? w1 : (seg == 1) ? w2 : (seg == 2) ? w3 :
                  (seg == 3) ? w4 : (seg == 4) ? w5 : (seg == 5) ? w6 : w7;
        }
        int j  = o & 7;
        int l  = (o >> 3) & 15;
        int qd = (o >> 7) & 3;
        int ks = (o >> 9) & 7;
        int ct = o >> 12;
        wout[idx] = f2b(src[(ct * 16 + l) * 256 + ks * 32 + qd * 8 + j]);
    } else {
        size_t base = (size_t)(blk - NB_ADJ - NB_WC) * D_;
        float v  = x[base + tid];
        float mu = block_sum256(v, scr) * (1.0f / D_);
        float d  = v - mu;
        float var = block_sum256(d * d, scr) * (1.0f / D_);
        float rstd = rsqrtf(var + 1e-5f);
        xn_b[base + tid] = f2b(d * rstd * g[tid] + bb[tid]);
    }
}

// ---------------- QKV GEMM + transposed V emission ----------------
__global__ __launch_bounds__(256)
void gemm_qkv(const ushort_t* __restrict__ A, const ushort_t* __restrict__ Wf,
              const float* __restrict__ bias, ushort_t* __restrict__ outb,
              ushort_t* __restrict__ vT) {
    __shared__ ushort_t Sa[64][264];
    int tid = threadIdx.x;
    int wave = tid >> 6, lane = tid & 63, l = lane & 15, quad = lane >> 4;
    int wm = wave >> 1, wn = wave & 1;
    int m0 = blockIdx.y * 64, n0 = blockIdx.x * 64;
    {
        int row = tid >> 2, c0 = (tid & 3) * 64;
        const ushort_t* ap = A + (size_t)(m0 + row) * 256 + c0;
#pragma unroll
        for (int j = 0; j < 8; ++j)
            *(uint4*)&Sa[row][c0 + 8 * j] = ((const uint4*)ap)[j];
    }
    __syncthreads();

    bf16x8 af[2][8];
#pragma unroll
    for (int mt = 0; mt < 2; ++mt)
#pragma unroll
        for (int ks = 0; ks < 8; ++ks)
            af[mt][ks] = *(const bf16x8*)&Sa[wm * 32 + mt * 16 + l][ks * 32 + quad * 8];

    f32x4 acc[2][2];
#pragma unroll
    for (int i = 0; i < 2; ++i)
#pragma unroll
        for (int j = 0; j < 2; ++j) acc[i][j] = (f32x4){0.f, 0.f, 0.f, 0.f};

#pragma unroll
    for (int nt = 0; nt < 2; ++nt) {
        int ct = (n0 >> 4) + wn * 2 + nt;
        bf16x8 wfr[8];
#pragma unroll
        for (int ks = 0; ks < 8; ++ks)
            wfr[ks] = *(const bf16x8*)(Wf + (((size_t)ct * 8 + ks) * 64 + lane) * 8);
#pragma unroll
        for (int ks = 0; ks < 8; ++ks) {
            acc[0][nt] = __builtin_amdgcn_mfma_f32_16x16x32_bf16(af[0][ks], wfr[ks], acc[0][nt], 0, 0, 0);
            acc[1][nt] = __builtin_amdgcn_mfma_f32_16x16x32_bf16(af[1][ks], wfr[ks], acc[1][nt], 0, 0, 0);
        }
    }

    __syncthreads();
    ushort_t* So = &Sa[0][0];
#pragma unroll
    for (int nt = 0; nt < 2; ++nt) {
        int col = wn * 32 + nt * 16 + l;
        int gcol = n0 + col;
        float bv = bias[gcol];
        float qs = ((gcol % 96) < 32) ? QSCALE : 1.0f;
#pragma unroll
        for (int mt = 0; mt < 2; ++mt)
#pragma unroll
            for (int r = 0; r < 4; ++r) {
                int row = wm * 32 + mt * 16 + quad * 4 + r;
                So[row * 72 + col] = f2b((acc[mt][nt][r] + bv) * qs);
            }
    }
    __syncthreads();
    {
        int row = tid >> 2, seg = tid & 3;
        uint4 v0 = *(uint4*)&So[row * 72 + seg * 16];
        uint4 v1 = *(uint4*)&So[row * 72 + seg * 16 + 8];
        ushort_t* op = outb + (size_t)(m0 + row) * 768 + n0 + seg * 16;
        ((uint4*)op)[0] = v0;
        ((uint4*)op)[1] = v1;
    }

    int vs = n0 % 96;
    if (vs != 0) {
        int vloc = (vs == 64) ? 0 : 32;
        int h  = (n0 + vloc) / 96;
        int b  = m0 >> 11;
        int s0 = m0 & (S_ - 1);
        ushort_t* vstage = &Sa[0][0] + 8192;
        {
            int c = tid & 31, seg = tid >> 5;
            ushort_t tmp[8];
#pragma unroll
            for (int i = 0; i < 8; ++i)
                tmp[i] = So[(seg * 8 + i) * 72 + vloc + c];
            uint_t u[4];
#pragma unroll
            for (int i = 0; i < 4; ++i)
                u[i] = (uint_t)tmp[2 * i] | ((uint_t)tmp[2 * i + 1] << 16);
            *(uint4*)&vstage[c * 72 + seg * 8] = make_uint4(u[0], u[1], u[2], u[3]);
        }
        __syncthreads();
        {
            int d = tid >> 3, tseg = tid & 7;
            uint4 v = *(uint4*)&vstage[d * 72 + tseg * 8];
            *(uint4*)&vT[((size_t)(b * 8 + h) * 32 + d) * S_ + s0 + tseg * 8] = v;
        }
    }
}

// ---------------- fully fused post-attention (frag-ordered weights) ----------------
__global__ __launch_bounds__(256)
void fused_gate(const ushort_t* __restrict__ attn_b, const float* __restrict__ xf,
                const ushort_t* __restrict__ wfc, const ushort_t* __restrict__ wz,
                const ushort_t* __restrict__ uz, const ushort_t* __restrict__ wr,
                const ushort_t* __restrict__ ur, const ushort_t* __restrict__ wg,
                const ushort_t* __restrict__ ug, const float* __restrict__ bfc,
                const float* __restrict__ bz, float* __restrict__ out) {
    __shared__ ushort_t Sa[16][264];
    __shared__ ushort_t Sx[16][264];
    __shared__ ushort_t Sy[16][264];
    __shared__ ushort_t St[16][264];
    int tid = threadIdx.x;
    int wave = tid >> 6, lane = tid & 63, l = lane & 15, quad = lane >> 4;
    int m0 = blockIdx.x * 16;
    int colbase = wave * 64;

    {
        int row = tid >> 4, c0 = (tid & 15) * 16;
        const ushort_t* ap = attn_b + (size_t)(m0 + row) * 256 + c0;
        uint4 a0 = ((const uint4*)ap)[0];
        uint4 a1 = ((const uint4*)ap)[1];
        *(uint4*)&Sa[row][c0] = a0;
        *(uint4*)&Sa[row][c0 + 8] = a1;
        const float4* xp = (const float4*)(xf + (size_t)(m0 + row) * 256 + c0);
        float4 f0 = xp[0], f1 = xp[1], f2_ = xp[2], f3 = xp[3];
        union { __hip_bfloat162 h[4]; uint4 u; } p0, p1;
        p0.h[0] = __float22bfloat162_rn(make_float2(f0.x, f0.y));
        p0.h[1] = __float22bfloat162_rn(make_float2(f0.z, f0.w));
        p0.h[2] = __float22bfloat162_rn(make_float2(f1.x, f1.y));
        p0.h[3] = __float22bfloat162_rn(make_float2(f1.z, f1.w));
        p1.h[0] = __float22bfloat162_rn(make_float2(f2_.x, f2_.y));
        p1.h[1] = __float22bfloat162_rn(make_float2(f2_.z, f2_.w));
        p1.h[2] = __float22bfloat162_rn(make_float2(f3.x, f3.y));
        p1.h[3] = __float22bfloat162_rn(make_float2(f3.z, f3.w));
        *(uint4*)&Sx[row][c0]     = p0.u;
        *(uint4*)&Sx[row][c0 + 8] = p1.u;
    }
    __syncthreads();

    {
        bf16x8 af[8];
#pragma unroll
        for (int ks = 0; ks < 8; ++ks)
            af[ks] = *(const bf16x8*)&Sa[l][ks * 32 + quad * 8];
        f32x4 ya[4];
#pragma unroll
        for (int nt = 0; nt < 4; ++nt) ya[nt] = (f32x4){0.f, 0.f, 0.f, 0.f};
#pragma unroll
        for (int nt = 0; nt < 4; ++nt) {
            size_t fb = ((size_t)(wave * 4 + nt) * 8) * 512 + lane * 8;
#pragma unroll
            for (int ks = 0; ks < 8; ++ks) {
                bf16x8 wfr = *(const bf16x8*)(wfc + fb + ks * 512);
                ya[nt] = __builtin_amdgcn_mfma_f32_16x16x32_bf16(af[ks], wfr, ya[nt], 0, 0, 0);
            }
        }
#pragma unroll
        for (int nt = 0; nt < 4; ++nt) {
            int col = colbase + nt * 16 + l;
            float bv = bfc[col];
#pragma unroll
            for (int r = 0; r < 4; ++r)
                Sy[quad * 4 + r][col] = f2b(fmaxf(ya[nt][r] + bv, 0.0f));
        }
    }
    __syncthreads();

    f32x4 az[4], ar[4], ag[4];
#pragma unroll
    for (int nt = 0; nt < 4; ++nt) {
        az[nt] = (f32x4){0.f, 0.f, 0.f, 0.f};
        ar[nt] = (f32x4){0.f, 0.f, 0.f, 0.f};
        ag[nt] = (f32x4){0.f, 0.f, 0.f, 0.f};
    }
#pragma unroll
    for (int nt = 0; nt < 4; ++nt) {
        size_t fb = ((size_t)(wave * 4 + nt) * 8) * 512 + lane * 8;
#pragma unroll
        for (int ks = 0; ks < 8; ++ks) {
            bf16x8 fy = *(const bf16x8*)&Sy[l][ks * 32 + quad * 8];
            bf16x8 fx = *(const bf16x8*)&Sx[l][ks * 32 + quad * 8];
            bf16x8 fz  = *(const bf16x8*)(wz + fb + ks * 512);
            bf16x8 fuz = *(const bf16x8*)(uz + fb + ks * 512);
            bf16x8 fr  = *(const bf16x8*)(wr + fb + ks * 512);
            bf16x8 fur = *(const bf16x8*)(ur + fb + ks * 512);
            bf16x8 fg  = *(const bf16x8*)(wg + fb + ks * 512);
            az[nt] = __builtin_amdgcn_mfma_f32_16x16x32_bf16(fy, fz,  az[nt], 0, 0, 0);
            az[nt] = __builtin_amdgcn_mfma_f32_16x16x32_bf16(fx, fuz, az[nt], 0, 0, 0);
            ar[nt] = __builtin_amdgcn_mfma_f32_16x16x32_bf16(fy, fr,  ar[nt], 0, 0, 0);
            ar[nt] = __builtin_amdgcn_mfma_f32_16x16x32_bf16(fx, fur, ar[nt], 0, 0, 0);
            ag[nt] = __builtin_amdgcn_mfma_f32_16x16x32_bf16(fy, fg,  ag[nt], 0, 0, 0);
        }
    }
#pragma unroll
    for (int nt = 0; nt < 4; ++nt) {
        int col = colbase + nt * 16 + l;
        float bzv = bz[col];
#pragma unroll
        for (int r = 0; r < 4; ++r) {
            int row = quad * 4 + r;
            az[nt][r] = 1.0f / (1.0f + __expf(-(az[nt][r] + bzv)));
            float rr  = 1.0f / (1.0f + __expf(-ar[nt][r]));
            St[row][col] = f2b(rr * b2f(Sx[row][col]));
        }
    }
    __syncthreads();

    f32x4 fcc[4];
#pragma unroll
    for (int nt = 0; nt < 4; ++nt) fcc[nt] = (f32x4){0.f, 0.f, 0.f, 0.f};
#pragma unroll
    for (int nt = 0; nt < 4; ++nt) {
        size_t fb = ((size_t)(wave * 4 + nt) * 8) * 512 + lane * 8;
#pragma unroll
        for (int ks = 0; ks < 8; ++ks) {
            bf16x8 ft = *(const bf16x8*)&St[l][ks * 32 + quad * 8];
            bf16x8 fu = *(const bf16x8*)(ug + fb + ks * 512);
            fcc[nt] = __builtin_amdgcn_mfma_f32_16x16x32_bf16(ft, fu, fcc[nt], 0, 0, 0);
        }
    }
#pragma unroll
    for (int nt = 0; nt < 4; ++nt) {
        int col = colbase + nt * 16 + l;
#pragma unroll
        for (int r = 0; r < 4; ++r) {
            int row = quad * 4 + r;
            float v = ag[nt][r] + fcc[nt][r];
            float e = __expf(2.0f * v);
            float h = 1.0f - 2.0f / (e + 1.0f);
            float zz = az[nt][r];
            size_t idx = (size_t)(m0 + row) * 256 + col;
            out[idx] = (1.0f - zz) * xf[idx] + zz * h;
        }
    }
}

// ---------------- MFMA flash attention: 32x32 in-register softmax, key-split wave pairs ----------------
// grid (S/64, B*H), block 256 = 4 waves; q-tile 64. Waves {0,1} own queries [0,32),
// waves {2,3} own [32,64); within each 64-key window wave (w&1)==0 handles keys 0-31,
// (w&1)==1 handles keys 32-63. Per-wave window work halves vs the 128q version while
// the grid doubles to 1024 blocks (4 independent blocks/CU) so phase-staggered blocks
// fill the VALU burst gaps. K rows stored PERMUTED (swap key bits 2<->3) so QK^T output
// regs hold keys in exactly the PV A-fragment order: softmax stays fully in registers.
// Tail: odd waves dump oacc/aones to LDS (conflict-free [pair][quad][lane][4] layout),
// even waves merge + write O. Q pre-scaled by 1/sqrt(32)*log2e in the QKV epilogue.
__global__ __launch_bounds__(256)
void attn_kernel(const ushort_t* __restrict__ qkvb, const ushort_t* __restrict__ vT,
                 const uint_t* __restrict__ abits, ushort_t* __restrict__ attn_b) {
    __shared__ ushort_t Ks[2][64][40];
    __shared__ ushort_t Vt[2][32][72];

    int tid = threadIdx.x;
    int wave = tid >> 6, lane = tid & 63;
    int lane5 = lane & 31, hi = lane >> 5;
    int hsh8 = hi * 8;
    int pair = wave >> 1, half = wave & 1;

    // bijective XCD swizzle: XCD x serves L in [128x,128x+128) -> heads 4x..4x+3
    int lid = blockIdx.y * 32 + blockIdx.x;   // 1024 blocks
    int L   = (lid & 7) * 128 + (lid >> 3);
    int q0  = (L & 31) * 64;
    int n   = L >> 5;
    int b = n >> 3, h = n & 7;
    int bp = n & 3, hp = n >> 2;

    const ushort_t* base = qkvb + (size_t)b * S_ * 768 + h * 96;
    int qbase = pair * 32;
    int myq = q0 + qbase + lane5;
    const int kb = half * 32;                 // this wave's key half within each window

    // Q B-fragments: lane (q=lane5, hi): Q[myq][hi*8+j] (dims 0-15) and [16+hi*8+j]
    bf16x8 qf1 = *(const bf16x8*)(base + (size_t)myq * 768 + hsh8);
    bf16x8 qf2 = *(const bf16x8*)(base + (size_t)myq * 768 + 16 + hsh8);

    bf16x8 ones;
#pragma unroll
    for (int i = 0; i < 8; ++i) ones[i] = (short)0x3F80;

    f32x16 oacc = zero16(), aones = zero16();

    // staging assignments (all 256 threads stage full 64-key window), permuted K rows
    int skey = tid >> 2, spart = tid & 3;
    int prow = (skey & ~12) | ((skey & 4) << 1) | ((skey & 8) >> 1);
    int kcol = (spart * 8) ^ (((prow >> 3) & 1) << 3);
    int vd = tid >> 3, vk = (tid & 7) * 8;
    const ushort_t* vptr = vT + ((size_t)n * 32 + vd) * S_ + vk;
    const uint_t* aptr = abits + ((size_t)b * S_ + myq) * 64 + half;  // word for this key half

    // ---- prologue: stage tile 0 into buf0, prefetch tile 1 into regs ----
    uint_t aw = aptr[0];
    {
        uint4 k0v = *(const uint4*)(base + (size_t)skey * 768 + 32 + spart * 8);
        uint4 v0v = *(const uint4*)(vptr);
        *(uint4*)&Ks[0][prow][kcol] = k0v;
        *(uint4*)&Vt[0][vd][vk] = v0v;
    }
    uint4 kv = *(const uint4*)(base + (size_t)(64 + skey) * 768 + 32 + spart * 8);
    uint4 vv = *(const uint4*)(vptr + 64);
    __syncthreads();

    int b3 = (lane >> 3) & 1;   // bit3 of lane5 (LDS row read swizzle key)

    for (int k0 = 0; k0 < S_; k0 += 64) {
        int cur = (k0 >> 6) & 1;
        bool more = (k0 + 64 < S_);
        uint_t awn;
        if (more) {
            *(uint4*)&Ks[cur ^ 1][prow][kcol] = kv;
            *(uint4*)&Vt[cur ^ 1][vd][vk] = vv;
            awn = aptr[(k0 + 64) >> 5];
            if (k0 + 128 < S_) {
                kv = *(const uint4*)(base + (size_t)(k0 + 128 + skey) * 768 + 32 + spart * 8);
                vv = *(const uint4*)(vptr + k0 + 128);
            }
        }

        // K A-fragments (rows permuted in LDS; read natural row index)
        bf16x8 kf1 = *(const bf16x8*)&Ks[cur][kb + lane5][(hi ^ b3) * 8];
        bf16x8 kf2 = *(const bf16x8*)&Ks[cur][kb + lane5][((2 + hi) ^ b3) * 8];
        f32x16 sc = zero16();
        sc = __builtin_amdgcn_mfma_f32_32x32x16_bf16(kf1, qf1, sc, 0, 0, 0);
        sc = __builtin_amdgcn_mfma_f32_32x32x16_bf16(kf2, qf2, sc, 0, 0, 0);

        // regs r hold original keys in PV order:
        //  lo lanes: r0-7 -> keys 0-7,  r8-15 -> keys 16-23 (of this 32-key half)
        //  hi lanes: r0-7 -> keys 8-15, r8-15 -> keys 24-31
        uint_t wsub = aw >> hsh8;
        union { uint_t u[8]; bf16x8 v[2]; } pp;
#pragma unroll
        for (int i = 0; i < 8; ++i) {
            const int c = 2 * i + ((i >> 2) * 8);   // 0,2,4,6,16,18,20,22
            float e0 = exp2f(sc[2 * i]);
            float e1 = exp2f(sc[2 * i + 1]);
            uint_t m0 = (uint_t)((int)(wsub << (31 - c)) >> 31);
            uint_t m1 = (uint_t)((int)(wsub << (30 - c)) >> 31);
            e0 = __uint_as_float(__float_as_uint(e0) & m0);
            e1 = __uint_as_float(__float_as_uint(e1) & m1);
            union { __hip_bfloat162 b2; uint_t u; } p;
            p.b2 = __float22bfloat162_rn(make_float2(e0, e1));
            pp.u[i] = p.u;
        }

        // V B-fragments (natural key order)
        bf16x8 vb1 = *(const bf16x8*)&Vt[cur][lane5][kb + hsh8];
        bf16x8 vb2 = *(const bf16x8*)&Vt[cur][lane5][kb + 16 + hsh8];

        __builtin_amdgcn_s_setprio(1);
        oacc  = __builtin_amdgcn_mfma_f32_32x32x16_bf16(pp.v[0], vb1,  oacc,  0, 0, 0);
        aones = __builtin_amdgcn_mfma_f32_32x32x16_bf16(pp.v[0], ones, aones, 0, 0, 0);
        oacc  = __builtin_amdgcn_mfma_f32_32x32x16_bf16(pp.v[1], vb2,  oacc,  0, 0, 0);
        aones = __builtin_amdgcn_mfma_f32_32x32x16_bf16(pp.v[1], ones, aones, 0, 0, 0);
        __builtin_amdgcn_s_setprio(0);

        if (more) aw = awn;
        __syncthreads();   // single barrier: this window's reads vs next window's writes
    }

    // ---- cross-wave (key-half) reduction: odd waves dump, even waves merge ----
    // red layout: [pair][quad j 0..7][lane][4] floats  (16 KB, conflict-free b128s)
    float* red = (float*)&Ks[0][0][0];
    if (half) {
        float* dst = red + pair * 2048 + lane * 4;
#pragma unroll
        for (int j = 0; j < 4; ++j) {
            f32x4 t;
            t[0] = oacc[4 * j]; t[1] = oacc[4 * j + 1];
            t[2] = oacc[4 * j + 2]; t[3] = oacc[4 * j + 3];
            *(f32x4*)(dst + j * 256) = t;
        }
#pragma unroll
        for (int j = 0; j < 4; ++j) {
            f32x4 t;
            t[0] = aones[4 * j]; t[1] = aones[4 * j + 1];
            t[2] = aones[4 * j + 2]; t[3] = aones[4 * j + 3];
            *(f32x4*)(dst + (4 + j) * 256) = t;
        }
    }
    __syncthreads();
    if (!half) {
        const float* src = red + pair * 2048 + lane * 4;
#pragma unroll
        for (int j = 0; j < 4; ++j) {
            f32x4 t = *(const f32x4*)(src + j * 256);
            oacc[4 * j] += t[0]; oacc[4 * j + 1] += t[1];
            oacc[4 * j + 2] += t[2]; oacc[4 * j + 3] += t[3];
        }
#pragma unroll
        for (int j = 0; j < 4; ++j) {
            f32x4 t = *(const f32x4*)(src + (4 + j) * 256);
            aones[4 * j] += t[0]; aones[4 * j + 1] += t[1];
            aones[4 * j + 2] += t[2]; aones[4 * j + 3] += t[3];
        }
    }
    __syncthreads();   // all reduction reads done before Ost overwrites red[0]

    // oacc reg r = O[query (r&3)+8*(r>>2)+4*hi][dim lane5]
    ushort_t* Ost = &Ks[0][0][0];   // 64 rows x stride 40 (5120 B)
    if (!half) {
#pragma unroll
        for (int r = 0; r < 16; ++r) {
            int qr = (r & 3) + 8 * (r >> 2) + 4 * hi;
            Ost[(qbase + qr) * 40 + lane5] = f2b(oacc[r] / aones[r]);
        }
    }
    __syncthreads();
    {
        int row = tid >> 2, part = tid & 3;
        uint4 v = *(uint4*)&Ost[row * 40 + part * 8];
        *(uint4*)&attn_b[((size_t)(bp * S_ + q0 + row)) * 256 + hp * 32 + part * 8] = v;
    }
}

// ---------------- launch ----------------
extern "C" void kernel_launch(void* const* d_in, const int* in_sizes, int n_in,
                              void* d_out, int out_size, void* d_ws, size_t ws_size,
                              hipStream_t stream) {
    const float* x     = (const float*)d_in[0];
    const int*   adj   = (const int*)d_in[1];
    const float* w_qkv = (const float*)d_in[2];
    const float* b_qkv = (const float*)d_in[3];
    const float* ln_g  = (const float*)d_in[4];
    const float* ln_b  = (const float*)d_in[5];
    const float* w_fc  = (const float*)d_in[6];
    const float* b_fc  = (const float*)d_in[7];
    const float* w_z   = (const float*)d_in[8];
    const float* b_z   = (const float*)d_in[9];
    const float* u_z   = (const float*)d_in[10];
    const float* w_r   = (const float*)d_in[11];
    const float* u_r   = (const float*)d_in[12];
    const float* w_g   = (const float*)d_in[13];
    const float* u_g   = (const float*)d_in[14];
    float* out = (float*)d_out;

    const size_t TOK  = (size_t)B_ * S_;       // 8192
    const size_t TOKD = TOK * D_;              // 2,097,152
    ushort_t* xn_b   = (ushort_t*)d_ws;
    ushort_t* qkv_b  = xn_b + TOKD;            // TOK*768
    ushort_t* attn_b = qkv_b + TOK * 768;
    ushort_t* wb     = attn_b + TOKD;          // 655,360 elems (frag-ordered)
    uint_t*   bits   = (uint_t*)(wb + WQ_SZ + 7 * WS_SZ);   // 524,288 words
    ushort_t* vTb    = (ushort_t*)(bits + (size_t)B_ * S_ * S_ / 32);  // 1024*2048

    ushort_t* wq_b  = wb;
    ushort_t* wfc_b = wb + WQ_SZ;
    ushort_t* wz_b  = wfc_b + WS_SZ;
    ushort_t* uz_b  = wz_b + WS_SZ;
    ushort_t* wr_b  = uz_b + WS_SZ;
    ushort_t* ur_b  = wr_b + WS_SZ;
    ushort_t* wg_b  = ur_b + WS_SZ;
    ushort_t* ug_b  = wg_b + WS_SZ;

    prep_kernel<<<NB_ADJ + NB_WC + NB_LN, 256, 0, stream>>>(
        adj, bits, w_qkv, w_fc, w_z, u_z, w_r, u_r, w_g, u_g, wb,
        x, ln_g, ln_b, xn_b);

    gemm_qkv<<<dim3(12, 128), 256, 0, stream>>>(xn_b, wq_b, b_qkv, qkv_b, vTb);

    attn_kernel<<<dim3(S_ / 64, B_ * H_), 256, 0, stream>>>(qkv_b, vTb, bits, attn_b);

    fused_gate<<<512, 256, 0, stream>>>(
        attn_b, x, wfc_b, wz_b, uz_b, wr_b, ur_b, wg_b, ug_b, b_fc, b_z, out);
}

// Round 7
// 223.622 us; speedup vs baseline: 1.0577x; 1.0577x over previous
//
#include <hip/hip_runtime.h>
#include <hip/hip_bf16.h>
#include <math.h>

#define B_  4
#define S_  2048
#define D_  256
#define H_  8
#define HD_ 32
// 1/sqrt(32) * log2(e): folded into Q so softmax is a bare exp2
#define QSCALE 0.25504175929589786f

typedef short  bf16x8 __attribute__((ext_vector_type(8)));
typedef float  f32x4  __attribute__((ext_vector_type(4)));
typedef float  f32x16 __attribute__((ext_vector_type(16)));
typedef unsigned short ushort_t;
typedef unsigned int   uint_t;

__device__ __forceinline__ ushort_t f2b(float f) {
    union { float f; unsigned u; } v; v.f = f;
    unsigned r = (v.u + 0x7FFFu + ((v.u >> 16) & 1u)) >> 16;
    return (ushort_t)r;
}
__device__ __forceinline__ float b2f(ushort_t s) {
    return __uint_as_float((uint_t)s << 16);
}
__device__ __forceinline__ f32x16 zero16() {
    f32x16 z;
#pragma unroll
    for (int i = 0; i < 16; ++i) z[i] = 0.f;
    return z;
}

// ---------------- reductions ----------------
__device__ __forceinline__ float wave_sum(float v) {
#pragma unroll
    for (int o = 32; o > 0; o >>= 1) v += __shfl_down(v, o, 64);
    return v;
}
__device__ __forceinline__ float block_sum256(float v, float* scr) {
    v = wave_sum(v);
    int lane = threadIdx.x & 63, wid = threadIdx.x >> 6;
    if (lane == 0) scr[wid] = v;
    __syncthreads();
    float r = scr[0] + scr[1] + scr[2] + scr[3];
    __syncthreads();
    return r;
}

// ---------------- merged prep: adj->bits (TRANSPOSED) | weight cvt+frag-reorder | layernorm ----------------
// bits layout: bits[(b*64 + word)*2048 + q]  -- word-major so attn's per-window mask
// load is lane-consecutive (coalesced 2 cache lines instead of a 32-line gather).
#define WQ_SZ 196608   // 768*256
#define WS_SZ 65536    // 256*256
#define NB_ADJ 8192    // one block per (b,q) row: 8 groups x 256 keys
#define NB_WC  2560    // (WQ_SZ+7*WS_SZ)/256
#define NB_LN  8192
__global__ __launch_bounds__(256)
void prep_kernel(const int* __restrict__ adj, uint_t* __restrict__ bits,
                 const float* __restrict__ w0, const float* __restrict__ w1,
                 const float* __restrict__ w2, const float* __restrict__ w3,
                 const float* __restrict__ w4, const float* __restrict__ w5,
                 const float* __restrict__ w6, const float* __restrict__ w7,
                 ushort_t* __restrict__ wout,
                 const float* __restrict__ x, const float* __restrict__ g,
                 const float* __restrict__ bb, ushort_t* __restrict__ xn_b) {
    __shared__ float scr[4];
    int blk = blockIdx.x, tid = threadIdx.x;
    if (blk < NB_ADJ) {
        int lane = tid & 63;
        int b = blk >> 11, q = blk & 2047;          // blk covers one (b,q) row
        uint_t* outp = bits + ((size_t)b * 64) * 2048 + q;
#pragma unroll
        for (int gp = 0; gp < 8; ++gp) {
            size_t i = ((size_t)blk * 8 + gp) * 256 + tid;
            unsigned long long m = __ballot(adj[i] != 0);
            int w = gp * 8 + ((tid & ~63) >> 5);    // word index within the 64-word row
            if (lane == 0)  outp[(size_t)w * 2048]       = (uint_t)m;
            if (lane == 32) outp[(size_t)(w + 1) * 2048] = (uint_t)(m >> 32);
        }
    } else if (blk < NB_ADJ + NB_WC) {
        int idx = (blk - NB_ADJ) * 256 + tid;
        const float* src; int o;
        if (idx < WQ_SZ) { src = w0; o = idx; }
        else {
            int j = idx - WQ_SZ, seg = j >> 16; o = j & (WS_SZ - 1);
            src = (seg == 0) ? w1 : (seg == 1) ? w2 : (seg == 2) ? w3 :
                  (seg == 3) ? w4 : (seg == 4) ? w5 : (seg == 5) ? w6 : w7;
        }
        int j  = o & 7;
        int l  = (o >> 3) & 15;
        int qd = (o >> 7) & 3;
        int ks = (o >> 9) & 7;
        int ct = o >> 12;
        wout[idx] = f2b(src[(ct * 16 + l) * 256 + ks * 32 + qd * 8 + j]);
    } else {
        size_t base = (size_t)(blk - NB_ADJ - NB_WC) * D_;
        float v  = x[base + tid];
        float mu = block_sum256(v, scr) * (1.0f / D_);
        float d  = v - mu;
        float var = block_sum256(d * d, scr) * (1.0f / D_);
        float rstd = rsqrtf(var + 1e-5f);
        xn_b[base + tid] = f2b(d * rstd * g[tid] + bb[tid]);
    }
}

// ---------------- QKV GEMM + transposed V emission ----------------
__global__ __launch_bounds__(256)
void gemm_qkv(const ushort_t* __restrict__ A, const ushort_t* __restrict__ Wf,
              const float* __restrict__ bias, ushort_t* __restrict__ outb,
              ushort_t* __restrict__ vT) {
    __shared__ ushort_t Sa[64][264];
    int tid = threadIdx.x;
    int wave = tid >> 6, lane = tid & 63, l = lane & 15, quad = lane >> 4;
    int wm = wave >> 1, wn = wave & 1;
    int m0 = blockIdx.y * 64, n0 = blockIdx.x * 64;
    {
        int row = tid >> 2, c0 = (tid & 3) * 64;
        const ushort_t* ap = A + (size_t)(m0 + row) * 256 + c0;
#pragma unroll
        for (int j = 0; j < 8; ++j)
            *(uint4*)&Sa[row][c0 + 8 * j] = ((const uint4*)ap)[j];
    }
    __syncthreads();

    bf16x8 af[2][8];
#pragma unroll
    for (int mt = 0; mt < 2; ++mt)
#pragma unroll
        for (int ks = 0; ks < 8; ++ks)
            af[mt][ks] = *(const bf16x8*)&Sa[wm * 32 + mt * 16 + l][ks * 32 + quad * 8];

    f32x4 acc[2][2];
#pragma unroll
    for (int i = 0; i < 2; ++i)
#pragma unroll
        for (int j = 0; j < 2; ++j) acc[i][j] = (f32x4){0.f, 0.f, 0.f, 0.f};

#pragma unroll
    for (int nt = 0; nt < 2; ++nt) {
        int ct = (n0 >> 4) + wn * 2 + nt;
        bf16x8 wfr[8];
#pragma unroll
        for (int ks = 0; ks < 8; ++ks)
            wfr[ks] = *(const bf16x8*)(Wf + (((size_t)ct * 8 + ks) * 64 + lane) * 8);
#pragma unroll
        for (int ks = 0; ks < 8; ++ks) {
            acc[0][nt] = __builtin_amdgcn_mfma_f32_16x16x32_bf16(af[0][ks], wfr[ks], acc[0][nt], 0, 0, 0);
            acc[1][nt] = __builtin_amdgcn_mfma_f32_16x16x32_bf16(af[1][ks], wfr[ks], acc[1][nt], 0, 0, 0);
        }
    }

    __syncthreads();
    ushort_t* So = &Sa[0][0];
#pragma unroll
    for (int nt = 0; nt < 2; ++nt) {
        int col = wn * 32 + nt * 16 + l;
        int gcol = n0 + col;
        float bv = bias[gcol];
        float qs = ((gcol % 96) < 32) ? QSCALE : 1.0f;
#pragma unroll
        for (int mt = 0; mt < 2; ++mt)
#pragma unroll
            for (int r = 0; r < 4; ++r) {
                int row = wm * 32 + mt * 16 + quad * 4 + r;
                So[row * 72 + col] = f2b((acc[mt][nt][r] + bv) * qs);
            }
    }
    __syncthreads();
    {
        int row = tid >> 2, seg = tid & 3;
        uint4 v0 = *(uint4*)&So[row * 72 + seg * 16];
        uint4 v1 = *(uint4*)&So[row * 72 + seg * 16 + 8];
        ushort_t* op = outb + (size_t)(m0 + row) * 768 + n0 + seg * 16;
        ((uint4*)op)[0] = v0;
        ((uint4*)op)[1] = v1;
    }

    int vs = n0 % 96;
    if (vs != 0) {
        int vloc = (vs == 64) ? 0 : 32;
        int h  = (n0 + vloc) / 96;
        int b  = m0 >> 11;
        int s0 = m0 & (S_ - 1);
        ushort_t* vstage = &Sa[0][0] + 8192;
        {
            int c = tid & 31, seg = tid >> 5;
            ushort_t tmp[8];
#pragma unroll
            for (int i = 0; i < 8; ++i)
                tmp[i] = So[(seg * 8 + i) * 72 + vloc + c];
            uint_t u[4];
#pragma unroll
            for (int i = 0; i < 4; ++i)
                u[i] = (uint_t)tmp[2 * i] | ((uint_t)tmp[2 * i + 1] << 16);
            *(uint4*)&vstage[c * 72 + seg * 8] = make_uint4(u[0], u[1], u[2], u[3]);
        }
        __syncthreads();
        {
            int d = tid >> 3, tseg = tid & 7;
            uint4 v = *(uint4*)&vstage[d * 72 + tseg * 8];
            *(uint4*)&vT[((size_t)(b * 8 + h) * 32 + d) * S_ + s0 + tseg * 8] = v;
        }
    }
}

// ---------------- fully fused post-attention (frag-ordered weights) ----------------
__global__ __launch_bounds__(256)
void fused_gate(const ushort_t* __restrict__ attn_b, const float* __restrict__ xf,
                const ushort_t* __restrict__ wfc, const ushort_t* __restrict__ wz,
                const ushort_t* __restrict__ uz, const ushort_t* __restrict__ wr,
                const ushort_t* __restrict__ ur, const ushort_t* __restrict__ wg,
                const ushort_t* __restrict__ ug, const float* __restrict__ bfc,
                const float* __restrict__ bz, float* __restrict__ out) {
    __shared__ ushort_t Sa[16][264];
    __shared__ ushort_t Sx[16][264];
    __shared__ ushort_t Sy[16][264];
    __shared__ ushort_t St[16][264];
    int tid = threadIdx.x;
    int wave = tid >> 6, lane = tid & 63, l = lane & 15, quad = lane >> 4;
    int m0 = blockIdx.x * 16;
    int colbase = wave * 64;

    {
        int row = tid >> 4, c0 = (tid & 15) * 16;
        const ushort_t* ap = attn_b + (size_t)(m0 + row) * 256 + c0;
        uint4 a0 = ((const uint4*)ap)[0];
        uint4 a1 = ((const uint4*)ap)[1];
        *(uint4*)&Sa[row][c0] = a0;
        *(uint4*)&Sa[row][c0 + 8] = a1;
        const float4* xp = (const float4*)(xf + (size_t)(m0 + row) * 256 + c0);
        float4 f0 = xp[0], f1 = xp[1], f2_ = xp[2], f3 = xp[3];
        union { __hip_bfloat162 h[4]; uint4 u; } p0, p1;
        p0.h[0] = __float22bfloat162_rn(make_float2(f0.x, f0.y));
        p0.h[1] = __float22bfloat162_rn(make_float2(f0.z, f0.w));
        p0.h[2] = __float22bfloat162_rn(make_float2(f1.x, f1.y));
        p0.h[3] = __float22bfloat162_rn(make_float2(f1.z, f1.w));
        p1.h[0] = __float22bfloat162_rn(make_float2(f2_.x, f2_.y));
        p1.h[1] = __float22bfloat162_rn(make_float2(f2_.z, f2_.w));
        p1.h[2] = __float22bfloat162_rn(make_float2(f3.x, f3.y));
        p1.h[3] = __float22bfloat162_rn(make_float2(f3.z, f3.w));
        *(uint4*)&Sx[row][c0]     = p0.u;
        *(uint4*)&Sx[row][c0 + 8] = p1.u;
    }
    __syncthreads();

    {
        bf16x8 af[8];
#pragma unroll
        for (int ks = 0; ks < 8; ++ks)
            af[ks] = *(const bf16x8*)&Sa[l][ks * 32 + quad * 8];
        f32x4 ya[4];
#pragma unroll
        for (int nt = 0; nt < 4; ++nt) ya[nt] = (f32x4){0.f, 0.f, 0.f, 0.f};
#pragma unroll
        for (int nt = 0; nt < 4; ++nt) {
            size_t fb = ((size_t)(wave * 4 + nt) * 8) * 512 + lane * 8;
#pragma unroll
            for (int ks = 0; ks < 8; ++ks) {
                bf16x8 wfr = *(const bf16x8*)(wfc + fb + ks * 512);
                ya[nt] = __builtin_amdgcn_mfma_f32_16x16x32_bf16(af[ks], wfr, ya[nt], 0, 0, 0);
            }
        }
#pragma unroll
        for (int nt = 0; nt < 4; ++nt) {
            int col = colbase + nt * 16 + l;
            float bv = bfc[col];
#pragma unroll
            for (int r = 0; r < 4; ++r)
                Sy[quad * 4 + r][col] = f2b(fmaxf(ya[nt][r] + bv, 0.0f));
        }
    }
    __syncthreads();

    f32x4 az[4], ar[4], ag[4];
#pragma unroll
    for (int nt = 0; nt < 4; ++nt) {
        az[nt] = (f32x4){0.f, 0.f, 0.f, 0.f};
        ar[nt] = (f32x4){0.f, 0.f, 0.f, 0.f};
        ag[nt] = (f32x4){0.f, 0.f, 0.f, 0.f};
    }
#pragma unroll
    for (int nt = 0; nt < 4; ++nt) {
        size_t fb = ((size_t)(wave * 4 + nt) * 8) * 512 + lane * 8;
#pragma unroll
        for (int ks = 0; ks < 8; ++ks) {
            bf16x8 fy = *(const bf16x8*)&Sy[l][ks * 32 + quad * 8];
            bf16x8 fx = *(const bf16x8*)&Sx[l][ks * 32 + quad * 8];
            bf16x8 fz  = *(const bf16x8*)(wz + fb + ks * 512);
            bf16x8 fuz = *(const bf16x8*)(uz + fb + ks * 512);
            bf16x8 fr  = *(const bf16x8*)(wr + fb + ks * 512);
            bf16x8 fur = *(const bf16x8*)(ur + fb + ks * 512);
            bf16x8 fg  = *(const bf16x8*)(wg + fb + ks * 512);
            az[nt] = __builtin_amdgcn_mfma_f32_16x16x32_bf16(fy, fz,  az[nt], 0, 0, 0);
            az[nt] = __builtin_amdgcn_mfma_f32_16x16x32_bf16(fx, fuz, az[nt], 0, 0, 0);
            ar[nt] = __builtin_amdgcn_mfma_f32_16x16x32_bf16(fy, fr,  ar[nt], 0, 0, 0);
            ar[nt] = __builtin_amdgcn_mfma_f32_16x16x32_bf16(fx, fur, ar[nt], 0, 0, 0);
            ag[nt] = __builtin_amdgcn_mfma_f32_16x16x32_bf16(fy, fg,  ag[nt], 0, 0, 0);
        }
    }
#pragma unroll
    for (int nt = 0; nt < 4; ++nt) {
        int col = colbase + nt * 16 + l;
        float bzv = bz[col];
#pragma unroll
        for (int r = 0; r < 4; ++r) {
            int row = quad * 4 + r;
            az[nt][r] = 1.0f / (1.0f + __expf(-(az[nt][r] + bzv)));
            float rr  = 1.0f / (1.0f + __expf(-ar[nt][r]));
            St[row][col] = f2b(rr * b2f(Sx[row][col]));
        }
    }
    __syncthreads();

    f32x4 fcc[4];
#pragma unroll
    for (int nt = 0; nt < 4; ++nt) fcc[nt] = (f32x4){0.f, 0.f, 0.f, 0.f};
#pragma unroll
    for (int nt = 0; nt < 4; ++nt) {
        size_t fb = ((size_t)(wave * 4 + nt) * 8) * 512 + lane * 8;
#pragma unroll
        for (int ks = 0; ks < 8; ++ks) {
            bf16x8 ft = *(const bf16x8*)&St[l][ks * 32 + quad * 8];
            bf16x8 fu = *(const bf16x8*)(ug + fb + ks * 512);
            fcc[nt] = __builtin_amdgcn_mfma_f32_16x16x32_bf16(ft, fu, fcc[nt], 0, 0, 0);
        }
    }
#pragma unroll
    for (int nt = 0; nt < 4; ++nt) {
        int col = colbase + nt * 16 + l;
#pragma unroll
        for (int r = 0; r < 4; ++r) {
            int row = quad * 4 + r;
            float v = ag[nt][r] + fcc[nt][r];
            float e = __expf(2.0f * v);
            float h = 1.0f - 2.0f / (e + 1.0f);
            float zz = az[nt][r];
            size_t idx = (size_t)(m0 + row) * 256 + col;
            out[idx] = (1.0f - zz) * xf[idx] + zz * h;
        }
    }
}

// ---------------- MFMA flash attention: 32x32 in-register softmax, KVBLK=128, key-split ----------------
// grid (S/64, B*H), block 256 = 4 waves; q-tile 64. Waves {0,1} own queries [0,32),
// waves {2,3} own [32,64); within each 128-key window wave half=(w&1) handles keys
// [half*64, half*64+64) as TWO independent 32-key subtile chains (QK->exp->PV) -- the
// ILP between subtiles hides MFMA/trans latency, and barriers drop to 16 (one per
// 128-key window). Mask words come from the TRANSPOSED bits layout (lane-consecutive,
// coalesced). K rows stored PERMUTED (swap key bits 2<->3) so QK^T output regs hold
// keys in exactly the PV A-fragment order: softmax fully in registers. Tail: odd waves
// dump oacc/aones to LDS, even waves merge + write O. Q pre-scaled by 1/sqrt(32)*log2e.
__global__ __launch_bounds__(256)
void attn_kernel(const ushort_t* __restrict__ qkvb, const ushort_t* __restrict__ vT,
                 const uint_t* __restrict__ abits, ushort_t* __restrict__ attn_b) {
    __shared__ ushort_t Ks[2][128][40];
    __shared__ ushort_t Vt[2][32][136];

    int tid = threadIdx.x;
    int wave = tid >> 6, lane = tid & 63;
    int lane5 = lane & 31, hi = lane >> 5;
    int hsh8 = hi * 8;
    int pair = wave >> 1, half = wave & 1;

    // bijective XCD swizzle: XCD x serves L in [128x,128x+128) -> heads 4x..4x+3
    int lid = blockIdx.y * 32 + blockIdx.x;   // 1024 blocks
    int L   = (lid & 7) * 128 + (lid >> 3);
    int q0  = (L & 31) * 64;
    int n   = L >> 5;
    int b = n >> 3, h = n & 7;
    int bp = n & 3, hp = n >> 2;

    const ushort_t* base = qkvb + (size_t)b * S_ * 768 + h * 96;
    int qbase = pair * 32;
    int myq = q0 + qbase + lane5;
    const int kofs = half * 64;               // this wave's key offset within each window

    // Q B-fragments: lane (q=lane5, hi): Q[myq][hi*8+j] (dims 0-15) and [16+hi*8+j]
    bf16x8 qf1 = *(const bf16x8*)(base + (size_t)myq * 768 + hsh8);
    bf16x8 qf2 = *(const bf16x8*)(base + (size_t)myq * 768 + 16 + hsh8);

    bf16x8 ones;
#pragma unroll
    for (int i = 0; i < 8; ++i) ones[i] = (short)0x3F80;

    f32x16 oacc = zero16(), aones = zero16();

    // staging assignments: 256 threads stage a full 128-key window (K: 2 threads/row x 32B;
    // V: 32 dims x 128 keys, 2 x uint4/thread). K rows stored at permuted index.
    int skey = tid >> 1, sj = tid & 1;        // K row 0..127, 32B half
    int prow = (skey & ~12) | ((skey & 4) << 1) | ((skey & 8) >> 1);
    int pxor = ((prow >> 3) & 1) << 3;
    int vd = tid >> 3, vk = (tid & 7) * 8;
    const ushort_t* vptr = vT + ((size_t)n * 32 + vd) * S_ + vk;
    const ushort_t* kptr = base + (size_t)skey * 768 + 32 + sj * 16;
    // transposed bits: word w at  tb[w*2048]; this wave's words per window: w0=(k0>>5)+half*2, w0+1
    const uint_t* tb = abits + ((size_t)b * 64) * 2048 + myq;

    // ---- prologue: stage window 0 (keys 0..127), prefetch window 1 into regs ----
    uint_t aw0 = tb[(size_t)(half * 2 + 0) * 2048];
    uint_t aw1 = tb[(size_t)(half * 2 + 1) * 2048];
    {
        uint4 ka = *(const uint4*)(kptr);
        uint4 kb_ = *(const uint4*)(kptr + 8);
        uint4 va = *(const uint4*)(vptr);
        uint4 vb_ = *(const uint4*)(vptr + 64);
        *(uint4*)&Ks[0][prow][(sj * 16 + 0) ^ pxor] = ka;
        *(uint4*)&Ks[0][prow][(sj * 16 + 8) ^ pxor] = kb_;
        *(uint4*)&Vt[0][vd][vk] = va;
        *(uint4*)&Vt[0][vd][vk + 64] = vb_;
    }
    uint4 kv0 = *(const uint4*)(kptr + (size_t)128 * 768);
    uint4 kv1 = *(const uint4*)(kptr + (size_t)128 * 768 + 8);
    uint4 vv0 = *(const uint4*)(vptr + 128);
    uint4 vv1 = *(const uint4*)(vptr + 192);
    __syncthreads();

    int b3 = (lane >> 3) & 1;   // bit3 of lane5 (LDS row read swizzle key)

    for (int k0 = 0; k0 < S_; k0 += 128) {
        int cur = (k0 >> 7) & 1;
        bool more = (k0 + 128 < S_);
        uint_t awn0, awn1;
        if (more) {
            *(uint4*)&Ks[cur ^ 1][prow][(sj * 16 + 0) ^ pxor] = kv0;
            *(uint4*)&Ks[cur ^ 1][prow][(sj * 16 + 8) ^ pxor] = kv1;
            *(uint4*)&Vt[cur ^ 1][vd][vk] = vv0;
            *(uint4*)&Vt[cur ^ 1][vd][vk + 64] = vv1;
            int wn = ((k0 + 128) >> 5) + half * 2;
            awn0 = tb[(size_t)(wn + 0) * 2048];
            awn1 = tb[(size_t)(wn + 1) * 2048];
            if (k0 + 256 < S_) {
                kv0 = *(const uint4*)(kptr + (size_t)(k0 + 256) * 768);
                kv1 = *(const uint4*)(kptr + (size_t)(k0 + 256) * 768 + 8);
                vv0 = *(const uint4*)(vptr + k0 + 256);
                vv1 = *(const uint4*)(vptr + k0 + 320);
            }
        }

#pragma unroll
        for (int kb2 = 0; kb2 < 2; ++kb2) {
            const int kb = kofs + kb2 * 32;   // key offset within window
            // K A-fragments (rows permuted in LDS; read natural row index)
            bf16x8 kf1 = *(const bf16x8*)&Ks[cur][kb + lane5][(hi ^ b3) * 8];
            bf16x8 kf2 = *(const bf16x8*)&Ks[cur][kb + lane5][((2 + hi) ^ b3) * 8];
            f32x16 sc = zero16();
            sc = __builtin_amdgcn_mfma_f32_32x32x16_bf16(kf1, qf1, sc, 0, 0, 0);
            sc = __builtin_amdgcn_mfma_f32_32x32x16_bf16(kf2, qf2, sc, 0, 0, 0);

            // regs r hold original keys in PV order:
            //  lo lanes: r0-7 -> keys 0-7,  r8-15 -> keys 16-23 (of this 32-key subtile)
            //  hi lanes: r0-7 -> keys 8-15, r8-15 -> keys 24-31
            uint_t wsub = (kb2 ? aw1 : aw0) >> hsh8;
            union { uint_t u[8]; bf16x8 v[2]; } pp;
#pragma unroll
            for (int i = 0; i < 8; ++i) {
                const int c = 2 * i + ((i >> 2) * 8);   // 0,2,4,6,16,18,20,22
                float e0 = __builtin_amdgcn_exp2f(sc[2 * i]);
                float e1 = __builtin_amdgcn_exp2f(sc[2 * i + 1]);
                uint_t m0 = (uint_t)((int)(wsub << (31 - c)) >> 31);
                uint_t m1 = (uint_t)((int)(wsub << (30 - c)) >> 31);
                e0 = __uint_as_float(__float_as_uint(e0) & m0);
                e1 = __uint_as_float(__float_as_uint(e1) & m1);
                union { __hip_bfloat162 b2; uint_t u; } p;
                p.b2 = __float22bfloat162_rn(make_float2(e0, e1));
                pp.u[i] = p.u;
            }

            // V B-fragments (natural key order)
            bf16x8 vb1 = *(const bf16x8*)&Vt[cur][lane5][kb + hsh8];
            bf16x8 vb2 = *(const bf16x8*)&Vt[cur][lane5][kb + 16 + hsh8];

            __builtin_amdgcn_s_setprio(1);
            oacc  = __builtin_amdgcn_mfma_f32_32x32x16_bf16(pp.v[0], vb1,  oacc,  0, 0, 0);
            aones = __builtin_amdgcn_mfma_f32_32x32x16_bf16(pp.v[0], ones, aones, 0, 0, 0);
            oacc  = __builtin_amdgcn_mfma_f32_32x32x16_bf16(pp.v[1], vb2,  oacc,  0, 0, 0);
            aones = __builtin_amdgcn_mfma_f32_32x32x16_bf16(pp.v[1], ones, aones, 0, 0, 0);
            __builtin_amdgcn_s_setprio(0);
        }

        if (more) { aw0 = awn0; aw1 = awn1; }
        __syncthreads();   // single barrier: this window's reads vs next window's writes
    }

    // ---- cross-wave (key-half) reduction: odd waves dump, even waves merge ----
    // red layout: [pair][quad j 0..7][lane][4] floats  (16 KB, conflict-free b128s)
    float* red = (float*)&Ks[0][0][0];
    if (half) {
        float* dst = red + pair * 2048 + lane * 4;
#pragma unroll
        for (int j = 0; j < 4; ++j) {
            f32x4 t;
            t[0] = oacc[4 * j]; t[1] = oacc[4 * j + 1];
            t[2] = oacc[4 * j + 2]; t[3] = oacc[4 * j + 3];
            *(f32x4*)(dst + j * 256) = t;
        }
#pragma unroll
        for (int j = 0; j < 4; ++j) {
            f32x4 t;
            t[0] = aones[4 * j]; t[1] = aones[4 * j + 1];
            t[2] = aones[4 * j + 2]; t[3] = aones[4 * j + 3];
            *(f32x4*)(dst + (4 + j) * 256) = t;
        }
    }
    __syncthreads();
    if (!half) {
        const float* src = red + pair * 2048 + lane * 4;
#pragma unroll
        for (int j = 0; j < 4; ++j) {
            f32x4 t = *(const f32x4*)(src + j * 256);
            oacc[4 * j] += t[0]; oacc[4 * j + 1] += t[1];
            oacc[4 * j + 2] += t[2]; oacc[4 * j + 3] += t[3];
        }
#pragma unroll
        for (int j = 0; j < 4; ++j) {
            f32x4 t = *(const f32x4*)(src + (4 + j) * 256);
            aones[4 * j] += t[0]; aones[4 * j + 1] += t[1];
            aones[4 * j + 2] += t[2]; aones[4 * j + 3] += t[3];
        }
    }
    __syncthreads();   // all reduction reads done before Ost overwrites red[0]

    // oacc reg r = O[query (r&3)+8*(r>>2)+4*hi][dim lane5]
    ushort_t* Ost = &Ks[0][0][0];   // 64 rows x stride 40 (5120 B)
    if (!half) {
#pragma unroll
        for (int r = 0; r < 16; ++r) {
            int qr = (r & 3) + 8 * (r >> 2) + 4 * hi;
            Ost[(qbase + qr) * 40 + lane5] = f2b(oacc[r] / aones[r]);
        }
    }
    __syncthreads();
    {
        int row = tid >> 2, part = tid & 3;
        uint4 v = *(uint4*)&Ost[row * 40 + part * 8];
        *(uint4*)&attn_b[((size_t)(bp * S_ + q0 + row)) * 256 + hp * 32 + part * 8] = v;
    }
}

// ---------------- launch ----------------
extern "C" void kernel_launch(void* const* d_in, const int* in_sizes, int n_in,
                              void* d_out, int out_size, void* d_ws, size_t ws_size,
                              hipStream_t stream) {
    const float* x     = (const float*)d_in[0];
    const int*   adj   = (const int*)d_in[1];
    const float* w_qkv = (const float*)d_in[2];
    const float* b_qkv = (const float*)d_in[3];
    const float* ln_g  = (const float*)d_in[4];
    const float* ln_b  = (const float*)d_in[5];
    const float* w_fc  = (const float*)d_in[6];
    const float* b_fc  = (const float*)d_in[7];
    const float* w_z   = (const float*)d_in[8];
    const float* b_z   = (const float*)d_in[9];
    const float* u_z   = (const float*)d_in[10];
    const float* w_r   = (const float*)d_in[11];
    const float* u_r   = (const float*)d_in[12];
    const float* w_g   = (const float*)d_in[13];
    const float* u_g   = (const float*)d_in[14];
    float* out = (float*)d_out;

    const size_t TOK  = (size_t)B_ * S_;       // 8192
    const size_t TOKD = TOK * D_;              // 2,097,152
    ushort_t* xn_b   = (ushort_t*)d_ws;
    ushort_t* qkv_b  = xn_b + TOKD;            // TOK*768
    ushort_t* attn_b = qkv_b + TOK * 768;
    ushort_t* wb     = attn_b + TOKD;          // 655,360 elems (frag-ordered)
    uint_t*   bits   = (uint_t*)(wb + WQ_SZ + 7 * WS_SZ);   // 524,288 words (transposed layout)
    ushort_t* vTb    = (ushort_t*)(bits + (size_t)B_ * S_ * S_ / 32);  // 1024*2048

    ushort_t* wq_b  = wb;
    ushort_t* wfc_b = wb + WQ_SZ;
    ushort_t* wz_b  = wfc_b + WS_SZ;
    ushort_t* uz_b  = wz_b + WS_SZ;
    ushort_t* wr_b  = uz_b + WS_SZ;
    ushort_t* ur_b  = wr_b + WS_SZ;
    ushort_t* wg_b  = ur_b + WS_SZ;
    ushort_t* ug_b  = wg_b + WS_SZ;

    prep_kernel<<<NB_ADJ + NB_WC + NB_LN, 256, 0, stream>>>(
        adj, bits, w_qkv, w_fc, w_z, u_z, w_r, u_r, w_g, u_g, wb,
        x, ln_g, ln_b, xn_b);

    gemm_qkv<<<dim3(12, 128), 256, 0, stream>>>(xn_b, wq_b, b_qkv, qkv_b, vTb);

    attn_kernel<<<dim3(S_ / 64, B_ * H_), 256, 0, stream>>>(qkv_b, vTb, bits, attn_b);

    fused_gate<<<512, 256, 0, stream>>>(
        attn_b, x, wfc_b, wz_b, uz_b, wr_b, ur_b, wg_b, ug_b, b_fc, b_z, out);
}

// Round 8
// 221.852 us; speedup vs baseline: 1.0661x; 1.0080x over previous
//
#include <hip/hip_runtime.h>
#include <hip/hip_bf16.h>
#include <math.h>

#define B_  4
#define S_  2048
#define D_  256
#define H_  8
#define HD_ 32
// 1/sqrt(32) * log2(e): folded into Q so softmax is a bare exp2
#define QSCALE 0.25504175929589786f

typedef short  bf16x8 __attribute__((ext_vector_type(8)));
typedef float  f32x4  __attribute__((ext_vector_type(4)));
typedef float  f32x16 __attribute__((ext_vector_type(16)));
typedef unsigned short ushort_t;
typedef unsigned int   uint_t;

__device__ __forceinline__ ushort_t f2b(float f) {
    union { float f; unsigned u; } v; v.f = f;
    unsigned r = (v.u + 0x7FFFu + ((v.u >> 16) & 1u)) >> 16;
    return (ushort_t)r;
}
__device__ __forceinline__ float b2f(ushort_t s) {
    return __uint_as_float((uint_t)s << 16);
}
__device__ __forceinline__ f32x16 zero16() {
    f32x16 z;
#pragma unroll
    for (int i = 0; i < 16; ++i) z[i] = 0.f;
    return z;
}

// ---------------- reductions ----------------
__device__ __forceinline__ float wave_sum(float v) {
#pragma unroll
    for (int o = 32; o > 0; o >>= 1) v += __shfl_down(v, o, 64);
    return v;
}
__device__ __forceinline__ float block_sum256(float v, float* scr) {
    v = wave_sum(v);
    int lane = threadIdx.x & 63, wid = threadIdx.x >> 6;
    if (lane == 0) scr[wid] = v;
    __syncthreads();
    float r = scr[0] + scr[1] + scr[2] + scr[3];
    __syncthreads();
    return r;
}

// ---------------- merged prep: adj->bits (TRANSPOSED) | weight cvt+frag-reorder | layernorm ----------------
// bits layout: bits[(b*64 + word)*2048 + q]  -- word-major so attn's per-window mask
// load is lane-consecutive (coalesced 2 cache lines instead of a 32-line gather).
#define WQ_SZ 196608   // 768*256
#define WS_SZ 65536    // 256*256
#define NB_ADJ 8192    // one block per (b,q) row: 8 groups x 256 keys
#define NB_WC  2560    // (WQ_SZ+7*WS_SZ)/256
#define NB_LN  8192
__global__ __launch_bounds__(256)
void prep_kernel(const int* __restrict__ adj, uint_t* __restrict__ bits,
                 const float* __restrict__ w0, const float* __restrict__ w1,
                 const float* __restrict__ w2, const float* __restrict__ w3,
                 const float* __restrict__ w4, const float* __restrict__ w5,
                 const float* __restrict__ w6, const float* __restrict__ w7,
                 ushort_t* __restrict__ wout,
                 const float* __restrict__ x, const float* __restrict__ g,
                 const float* __restrict__ bb, ushort_t* __restrict__ xn_b) {
    __shared__ float scr[4];
    int blk = blockIdx.x, tid = threadIdx.x;
    if (blk < NB_ADJ) {
        int lane = tid & 63;
        int b = blk >> 11, q = blk & 2047;          // blk covers one (b,q) row
        uint_t* outp = bits + ((size_t)b * 64) * 2048 + q;
#pragma unroll
        for (int gp = 0; gp < 8; ++gp) {
            size_t i = ((size_t)blk * 8 + gp) * 256 + tid;
            unsigned long long m = __ballot(adj[i] != 0);
            int w = gp * 8 + ((tid & ~63) >> 5);    // word index within the 64-word row
            if (lane == 0)  outp[(size_t)w * 2048]       = (uint_t)m;
            if (lane == 32) outp[(size_t)(w + 1) * 2048] = (uint_t)(m >> 32);
        }
    } else if (blk < NB_ADJ + NB_WC) {
        int idx = (blk - NB_ADJ) * 256 + tid;
        const float* src; int o;
        if (idx < WQ_SZ) { src = w0; o = idx; }
        else {
            int j = idx - WQ_SZ, seg = j >> 16; o = j & (WS_SZ - 1);
            src = (seg == 0) ? w1 : (seg == 1) ? w2 : (seg == 2) ? w3 :
                  (seg == 3) ? w4 : (seg == 4) ? w5 : (seg == 5) ? w6 : w7;
        }
        int j  = o & 7;
        int l  = (o >> 3) & 15;
        int qd = (o >> 7) & 3;
        int ks = (o >> 9) & 7;
        int ct = o >> 12;
        wout[idx] = f2b(src[(ct * 16 + l) * 256 + ks * 32 + qd * 8 + j]);
    } else {
        size_t base = (size_t)(blk - NB_ADJ - NB_WC) * D_;
        float v  = x[base + tid];
        float mu = block_sum256(v, scr) * (1.0f / D_);
        float d  = v - mu;
        float var = block_sum256(d * d, scr) * (1.0f / D_);
        float rstd = rsqrtf(var + 1e-5f);
        xn_b[base + tid] = f2b(d * rstd * g[tid] + bb[tid]);
    }
}

// ---------------- QKV GEMM + transposed V emission ----------------
__global__ __launch_bounds__(256)
void gemm_qkv(const ushort_t* __restrict__ A, const ushort_t* __restrict__ Wf,
              const float* __restrict__ bias, ushort_t* __restrict__ outb,
              ushort_t* __restrict__ vT) {
    __shared__ ushort_t Sa[64][264];
    int tid = threadIdx.x;
    int wave = tid >> 6, lane = tid & 63, l = lane & 15, quad = lane >> 4;
    int wm = wave >> 1, wn = wave & 1;
    int m0 = blockIdx.y * 64, n0 = blockIdx.x * 64;
    {
        int row = tid >> 2, c0 = (tid & 3) * 64;
        const ushort_t* ap = A + (size_t)(m0 + row) * 256 + c0;
#pragma unroll
        for (int j = 0; j < 8; ++j)
            *(uint4*)&Sa[row][c0 + 8 * j] = ((const uint4*)ap)[j];
    }
    __syncthreads();

    bf16x8 af[2][8];
#pragma unroll
    for (int mt = 0; mt < 2; ++mt)
#pragma unroll
        for (int ks = 0; ks < 8; ++ks)
            af[mt][ks] = *(const bf16x8*)&Sa[wm * 32 + mt * 16 + l][ks * 32 + quad * 8];

    f32x4 acc[2][2];
#pragma unroll
    for (int i = 0; i < 2; ++i)
#pragma unroll
        for (int j = 0; j < 2; ++j) acc[i][j] = (f32x4){0.f, 0.f, 0.f, 0.f};

#pragma unroll
    for (int nt = 0; nt < 2; ++nt) {
        int ct = (n0 >> 4) + wn * 2 + nt;
        bf16x8 wfr[8];
#pragma unroll
        for (int ks = 0; ks < 8; ++ks)
            wfr[ks] = *(const bf16x8*)(Wf + (((size_t)ct * 8 + ks) * 64 + lane) * 8);
#pragma unroll
        for (int ks = 0; ks < 8; ++ks) {
            acc[0][nt] = __builtin_amdgcn_mfma_f32_16x16x32_bf16(af[0][ks], wfr[ks], acc[0][nt], 0, 0, 0);
            acc[1][nt] = __builtin_amdgcn_mfma_f32_16x16x32_bf16(af[1][ks], wfr[ks], acc[1][nt], 0, 0, 0);
        }
    }

    __syncthreads();
    ushort_t* So = &Sa[0][0];
#pragma unroll
    for (int nt = 0; nt < 2; ++nt) {
        int col = wn * 32 + nt * 16 + l;
        int gcol = n0 + col;
        float bv = bias[gcol];
        float qs = ((gcol % 96) < 32) ? QSCALE : 1.0f;
#pragma unroll
        for (int mt = 0; mt < 2; ++mt)
#pragma unroll
            for (int r = 0; r < 4; ++r) {
                int row = wm * 32 + mt * 16 + quad * 4 + r;
                So[row * 72 + col] = f2b((acc[mt][nt][r] + bv) * qs);
            }
    }
    __syncthreads();
    {
        int row = tid >> 2, seg = tid & 3;
        uint4 v0 = *(uint4*)&So[row * 72 + seg * 16];
        uint4 v1 = *(uint4*)&So[row * 72 + seg * 16 + 8];
        ushort_t* op = outb + (size_t)(m0 + row) * 768 + n0 + seg * 16;
        ((uint4*)op)[0] = v0;
        ((uint4*)op)[1] = v1;
    }

    int vs = n0 % 96;
    if (vs != 0) {
        int vloc = (vs == 64) ? 0 : 32;
        int h  = (n0 + vloc) / 96;
        int b  = m0 >> 11;
        int s0 = m0 & (S_ - 1);
        ushort_t* vstage = &Sa[0][0] + 8192;
        {
            int c = tid & 31, seg = tid >> 5;
            ushort_t tmp[8];
#pragma unroll
            for (int i = 0; i < 8; ++i)
                tmp[i] = So[(seg * 8 + i) * 72 + vloc + c];
            uint_t u[4];
#pragma unroll
            for (int i = 0; i < 4; ++i)
                u[i] = (uint_t)tmp[2 * i] | ((uint_t)tmp[2 * i + 1] << 16);
            *(uint4*)&vstage[c * 72 + seg * 8] = make_uint4(u[0], u[1], u[2], u[3]);
        }
        __syncthreads();
        {
            int d = tid >> 3, tseg = tid & 7;
            uint4 v = *(uint4*)&vstage[d * 72 + tseg * 8];
            *(uint4*)&vT[((size_t)(b * 8 + h) * 32 + d) * S_ + s0 + tseg * 8] = v;
        }
    }
}

// ---------------- fully fused post-attention (frag-ordered weights), 8-wave ----------------
// 512 threads = 8 waves; each wave owns a 32-col strip (nt in [0,2), ct = wave*2+nt).
// Doubles waves/SIMD (2->4) and halves each wave's L2 weight-load chain vs the 4-wave
// version -- the inner loop is latency-bound on ~200-cy L2 fragment loads.
__global__ __launch_bounds__(512)
void fused_gate(const ushort_t* __restrict__ attn_b, const float* __restrict__ xf,
                const ushort_t* __restrict__ wfc, const ushort_t* __restrict__ wz,
                const ushort_t* __restrict__ uz, const ushort_t* __restrict__ wr,
                const ushort_t* __restrict__ ur, const ushort_t* __restrict__ wg,
                const ushort_t* __restrict__ ug, const float* __restrict__ bfc,
                const float* __restrict__ bz, float* __restrict__ out) {
    __shared__ ushort_t Sa[16][264];
    __shared__ ushort_t Sx[16][264];
    __shared__ ushort_t Sy[16][264];
    __shared__ ushort_t St[16][264];
    int tid = threadIdx.x;
    int wave = tid >> 6, lane = tid & 63, l = lane & 15, quad = lane >> 4;
    int m0 = blockIdx.x * 16;
    int colbase = wave * 32;

    {
        int row = tid >> 5, c0 = (tid & 31) * 8;
        const ushort_t* ap = attn_b + (size_t)(m0 + row) * 256 + c0;
        *(uint4*)&Sa[row][c0] = *((const uint4*)ap);
        const float4* xp = (const float4*)(xf + (size_t)(m0 + row) * 256 + c0);
        float4 f0 = xp[0], f1 = xp[1];
        union { __hip_bfloat162 h[4]; uint4 u; } p0;
        p0.h[0] = __float22bfloat162_rn(make_float2(f0.x, f0.y));
        p0.h[1] = __float22bfloat162_rn(make_float2(f0.z, f0.w));
        p0.h[2] = __float22bfloat162_rn(make_float2(f1.x, f1.y));
        p0.h[3] = __float22bfloat162_rn(make_float2(f1.z, f1.w));
        *(uint4*)&Sx[row][c0] = p0.u;
    }
    __syncthreads();

    {
        bf16x8 af[8];
#pragma unroll
        for (int ks = 0; ks < 8; ++ks)
            af[ks] = *(const bf16x8*)&Sa[l][ks * 32 + quad * 8];
        f32x4 ya[2];
#pragma unroll
        for (int nt = 0; nt < 2; ++nt) ya[nt] = (f32x4){0.f, 0.f, 0.f, 0.f};
#pragma unroll
        for (int nt = 0; nt < 2; ++nt) {
            size_t fb = ((size_t)(wave * 2 + nt) * 8) * 512 + lane * 8;
#pragma unroll
            for (int ks = 0; ks < 8; ++ks) {
                bf16x8 wfr = *(const bf16x8*)(wfc + fb + ks * 512);
                ya[nt] = __builtin_amdgcn_mfma_f32_16x16x32_bf16(af[ks], wfr, ya[nt], 0, 0, 0);
            }
        }
#pragma unroll
        for (int nt = 0; nt < 2; ++nt) {
            int col = colbase + nt * 16 + l;
            float bv = bfc[col];
#pragma unroll
            for (int r = 0; r < 4; ++r)
                Sy[quad * 4 + r][col] = f2b(fmaxf(ya[nt][r] + bv, 0.0f));
        }
    }
    __syncthreads();

    f32x4 az[2], ar[2], ag[2];
#pragma unroll
    for (int nt = 0; nt < 2; ++nt) {
        az[nt] = (f32x4){0.f, 0.f, 0.f, 0.f};
        ar[nt] = (f32x4){0.f, 0.f, 0.f, 0.f};
        ag[nt] = (f32x4){0.f, 0.f, 0.f, 0.f};
    }
#pragma unroll
    for (int nt = 0; nt < 2; ++nt) {
        size_t fb = ((size_t)(wave * 2 + nt) * 8) * 512 + lane * 8;
#pragma unroll
        for (int ks = 0; ks < 8; ++ks) {
            bf16x8 fy = *(const bf16x8*)&Sy[l][ks * 32 + quad * 8];
            bf16x8 fx = *(const bf16x8*)&Sx[l][ks * 32 + quad * 8];
            bf16x8 fz  = *(const bf16x8*)(wz + fb + ks * 512);
            bf16x8 fuz = *(const bf16x8*)(uz + fb + ks * 512);
            bf16x8 fr  = *(const bf16x8*)(wr + fb + ks * 512);
            bf16x8 fur = *(const bf16x8*)(ur + fb + ks * 512);
            bf16x8 fg  = *(const bf16x8*)(wg + fb + ks * 512);
            az[nt] = __builtin_amdgcn_mfma_f32_16x16x32_bf16(fy, fz,  az[nt], 0, 0, 0);
            az[nt] = __builtin_amdgcn_mfma_f32_16x16x32_bf16(fx, fuz, az[nt], 0, 0, 0);
            ar[nt] = __builtin_amdgcn_mfma_f32_16x16x32_bf16(fy, fr,  ar[nt], 0, 0, 0);
            ar[nt] = __builtin_amdgcn_mfma_f32_16x16x32_bf16(fx, fur, ar[nt], 0, 0, 0);
            ag[nt] = __builtin_amdgcn_mfma_f32_16x16x32_bf16(fy, fg,  ag[nt], 0, 0, 0);
        }
    }
#pragma unroll
    for (int nt = 0; nt < 2; ++nt) {
        int col = colbase + nt * 16 + l;
        float bzv = bz[col];
#pragma unroll
        for (int r = 0; r < 4; ++r) {
            int row = quad * 4 + r;
            az[nt][r] = 1.0f / (1.0f + __expf(-(az[nt][r] + bzv)));
            float rr  = 1.0f / (1.0f + __expf(-ar[nt][r]));
            St[row][col] = f2b(rr * b2f(Sx[row][col]));
        }
    }
    __syncthreads();

    f32x4 fcc[2];
#pragma unroll
    for (int nt = 0; nt < 2; ++nt) fcc[nt] = (f32x4){0.f, 0.f, 0.f, 0.f};
#pragma unroll
    for (int nt = 0; nt < 2; ++nt) {
        size_t fb = ((size_t)(wave * 2 + nt) * 8) * 512 + lane * 8;
#pragma unroll
        for (int ks = 0; ks < 8; ++ks) {
            bf16x8 ft = *(const bf16x8*)&St[l][ks * 32 + quad * 8];
            bf16x8 fu = *(const bf16x8*)(ug + fb + ks * 512);
            fcc[nt] = __builtin_amdgcn_mfma_f32_16x16x32_bf16(ft, fu, fcc[nt], 0, 0, 0);
        }
    }
#pragma unroll
    for (int nt = 0; nt < 2; ++nt) {
        int col = colbase + nt * 16 + l;
#pragma unroll
        for (int r = 0; r < 4; ++r) {
            int row = quad * 4 + r;
            float v = ag[nt][r] + fcc[nt][r];
            float e = __expf(2.0f * v);
            float h = 1.0f - 2.0f / (e + 1.0f);
            float zz = az[nt][r];
            size_t idx = (size_t)(m0 + row) * 256 + col;
            out[idx] = (1.0f - zz) * xf[idx] + zz * h;
        }
    }
}

// ---------------- MFMA flash attention: 32x32 in-register softmax, KVBLK=128, key-split ----------------
// (unchanged from round 7: 53.0 us, MfmaUtil 19)
__global__ __launch_bounds__(256)
void attn_kernel(const ushort_t* __restrict__ qkvb, const ushort_t* __restrict__ vT,
                 const uint_t* __restrict__ abits, ushort_t* __restrict__ attn_b) {
    __shared__ ushort_t Ks[2][128][40];
    __shared__ ushort_t Vt[2][32][136];

    int tid = threadIdx.x;
    int wave = tid >> 6, lane = tid & 63;
    int lane5 = lane & 31, hi = lane >> 5;
    int hsh8 = hi * 8;
    int pair = wave >> 1, half = wave & 1;

    // bijective XCD swizzle: XCD x serves L in [128x,128x+128) -> heads 4x..4x+3
    int lid = blockIdx.y * 32 + blockIdx.x;   // 1024 blocks
    int L   = (lid & 7) * 128 + (lid >> 3);
    int q0  = (L & 31) * 64;
    int n   = L >> 5;
    int b = n >> 3, h = n & 7;
    int bp = n & 3, hp = n >> 2;

    const ushort_t* base = qkvb + (size_t)b * S_ * 768 + h * 96;
    int qbase = pair * 32;
    int myq = q0 + qbase + lane5;
    const int kofs = half * 64;               // this wave's key offset within each window

    // Q B-fragments: lane (q=lane5, hi): Q[myq][hi*8+j] (dims 0-15) and [16+hi*8+j]
    bf16x8 qf1 = *(const bf16x8*)(base + (size_t)myq * 768 + hsh8);
    bf16x8 qf2 = *(const bf16x8*)(base + (size_t)myq * 768 + 16 + hsh8);

    bf16x8 ones;
#pragma unroll
    for (int i = 0; i < 8; ++i) ones[i] = (short)0x3F80;

    f32x16 oacc = zero16(), aones = zero16();

    // staging assignments: 256 threads stage a full 128-key window (K: 2 threads/row x 32B;
    // V: 32 dims x 128 keys, 2 x uint4/thread). K rows stored at permuted index.
    int skey = tid >> 1, sj = tid & 1;        // K row 0..127, 32B half
    int prow = (skey & ~12) | ((skey & 4) << 1) | ((skey & 8) >> 1);
    int pxor = ((prow >> 3) & 1) << 3;
    int vd = tid >> 3, vk = (tid & 7) * 8;
    const ushort_t* vptr = vT + ((size_t)n * 32 + vd) * S_ + vk;
    const ushort_t* kptr = base + (size_t)skey * 768 + 32 + sj * 16;
    // transposed bits: word w at  tb[w*2048]; this wave's words per window: w0=(k0>>5)+half*2, w0+1
    const uint_t* tb = abits + ((size_t)b * 64) * 2048 + myq;

    // ---- prologue: stage window 0 (keys 0..127), prefetch window 1 into regs ----
    uint_t aw0 = tb[(size_t)(half * 2 + 0) * 2048];
    uint_t aw1 = tb[(size_t)(half * 2 + 1) * 2048];
    {
        uint4 ka = *(const uint4*)(kptr);
        uint4 kb_ = *(const uint4*)(kptr + 8);
        uint4 va = *(const uint4*)(vptr);
        uint4 vb_ = *(const uint4*)(vptr + 64);
        *(uint4*)&Ks[0][prow][(sj * 16 + 0) ^ pxor] = ka;
        *(uint4*)&Ks[0][prow][(sj * 16 + 8) ^ pxor] = kb_;
        *(uint4*)&Vt[0][vd][vk] = va;
        *(uint4*)&Vt[0][vd][vk + 64] = vb_;
    }
    uint4 kv0 = *(const uint4*)(kptr + (size_t)128 * 768);
    uint4 kv1 = *(const uint4*)(kptr + (size_t)128 * 768 + 8);
    uint4 vv0 = *(const uint4*)(vptr + 128);
    uint4 vv1 = *(const uint4*)(vptr + 192);
    __syncthreads();

    int b3 = (lane >> 3) & 1;   // bit3 of lane5 (LDS row read swizzle key)

    for (int k0 = 0; k0 < S_; k0 += 128) {
        int cur = (k0 >> 7) & 1;
        bool more = (k0 + 128 < S_);
        uint_t awn0, awn1;
        if (more) {
            *(uint4*)&Ks[cur ^ 1][prow][(sj * 16 + 0) ^ pxor] = kv0;
            *(uint4*)&Ks[cur ^ 1][prow][(sj * 16 + 8) ^ pxor] = kv1;
            *(uint4*)&Vt[cur ^ 1][vd][vk] = vv0;
            *(uint4*)&Vt[cur ^ 1][vd][vk + 64] = vv1;
            int wn = ((k0 + 128) >> 5) + half * 2;
            awn0 = tb[(size_t)(wn + 0) * 2048];
            awn1 = tb[(size_t)(wn + 1) * 2048];
            if (k0 + 256 < S_) {
                kv0 = *(const uint4*)(kptr + (size_t)(k0 + 256) * 768);
                kv1 = *(const uint4*)(kptr + (size_t)(k0 + 256) * 768 + 8);
                vv0 = *(const uint4*)(vptr + k0 + 256);
                vv1 = *(const uint4*)(vptr + k0 + 320);
            }
        }

#pragma unroll
        for (int kb2 = 0; kb2 < 2; ++kb2) {
            const int kb = kofs + kb2 * 32;   // key offset within window
            // K A-fragments (rows permuted in LDS; read natural row index)
            bf16x8 kf1 = *(const bf16x8*)&Ks[cur][kb + lane5][(hi ^ b3) * 8];
            bf16x8 kf2 = *(const bf16x8*)&Ks[cur][kb + lane5][((2 + hi) ^ b3) * 8];
            f32x16 sc = zero16();
            sc = __builtin_amdgcn_mfma_f32_32x32x16_bf16(kf1, qf1, sc, 0, 0, 0);
            sc = __builtin_amdgcn_mfma_f32_32x32x16_bf16(kf2, qf2, sc, 0, 0, 0);

            // regs r hold original keys in PV order:
            //  lo lanes: r0-7 -> keys 0-7,  r8-15 -> keys 16-23 (of this 32-key subtile)
            //  hi lanes: r0-7 -> keys 8-15, r8-15 -> keys 24-31
            uint_t wsub = (kb2 ? aw1 : aw0) >> hsh8;
            union { uint_t u[8]; bf16x8 v[2]; } pp;
#pragma unroll
            for (int i = 0; i < 8; ++i) {
                const int c = 2 * i + ((i >> 2) * 8);   // 0,2,4,6,16,18,20,22
                float e0 = __builtin_amdgcn_exp2f(sc[2 * i]);
                float e1 = __builtin_amdgcn_exp2f(sc[2 * i + 1]);
                uint_t m0 = (uint_t)((int)(wsub << (31 - c)) >> 31);
                uint_t m1 = (uint_t)((int)(wsub << (30 - c)) >> 31);
                e0 = __uint_as_float(__float_as_uint(e0) & m0);
                e1 = __uint_as_float(__float_as_uint(e1) & m1);
                union { __hip_bfloat162 b2; uint_t u; } p;
                p.b2 = __float22bfloat162_rn(make_float2(e0, e1));
                pp.u[i] = p.u;
            }

            // V B-fragments (natural key order)
            bf16x8 vb1 = *(const bf16x8*)&Vt[cur][lane5][kb + hsh8];
            bf16x8 vb2 = *(const bf16x8*)&Vt[cur][lane5][kb + 16 + hsh8];

            __builtin_amdgcn_s_setprio(1);
            oacc  = __builtin_amdgcn_mfma_f32_32x32x16_bf16(pp.v[0], vb1,  oacc,  0, 0, 0);
            aones = __builtin_amdgcn_mfma_f32_32x32x16_bf16(pp.v[0], ones, aones, 0, 0, 0);
            oacc  = __builtin_amdgcn_mfma_f32_32x32x16_bf16(pp.v[1], vb2,  oacc,  0, 0, 0);
            aones = __builtin_amdgcn_mfma_f32_32x32x16_bf16(pp.v[1], ones, aones, 0, 0, 0);
            __builtin_amdgcn_s_setprio(0);
        }

        if (more) { aw0 = awn0; aw1 = awn1; }
        __syncthreads();   // single barrier: this window's reads vs next window's writes
    }

    // ---- cross-wave (key-half) reduction: odd waves dump, even waves merge ----
    // red layout: [pair][quad j 0..7][lane][4] floats  (16 KB, conflict-free b128s)
    float* red = (float*)&Ks[0][0][0];
    if (half) {
        float* dst = red + pair * 2048 + lane * 4;
#pragma unroll
        for (int j = 0; j < 4; ++j) {
            f32x4 t;
            t[0] = oacc[4 * j]; t[1] = oacc[4 * j + 1];
            t[2] = oacc[4 * j + 2]; t[3] = oacc[4 * j + 3];
            *(f32x4*)(dst + j * 256) = t;
        }
#pragma unroll
        for (int j = 0; j < 4; ++j) {
            f32x4 t;
            t[0] = aones[4 * j]; t[1] = aones[4 * j + 1];
            t[2] = aones[4 * j + 2]; t[3] = aones[4 * j + 3];
            *(f32x4*)(dst + (4 + j) * 256) = t;
        }
    }
    __syncthreads();
    if (!half) {
        const float* src = red + pair * 2048 + lane * 4;
#pragma unroll
        for (int j = 0; j < 4; ++j) {
            f32x4 t = *(const f32x4*)(src + j * 256);
            oacc[4 * j] += t[0]; oacc[4 * j + 1] += t[1];
            oacc[4 * j + 2] += t[2]; oacc[4 * j + 3] += t[3];
        }
#pragma unroll
        for (int j = 0; j < 4; ++j) {
            f32x4 t = *(const f32x4*)(src + (4 + j) * 256);
            aones[4 * j] += t[0]; aones[4 * j + 1] += t[1];
            aones[4 * j + 2] += t[2]; aones[4 * j + 3] += t[3];
        }
    }
    __syncthreads();   // all reduction reads done before Ost overwrites red[0]

    // oacc reg r = O[query (r&3)+8*(r>>2)+4*hi][dim lane5]
    ushort_t* Ost = &Ks[0][0][0];   // 64 rows x stride 40 (5120 B)
    if (!half) {
#pragma unroll
        for (int r = 0; r < 16; ++r) {
            int qr = (r & 3) + 8 * (r >> 2) + 4 * hi;
            Ost[(qbase + qr) * 40 + lane5] = f2b(oacc[r] / aones[r]);
        }
    }
    __syncthreads();
    {
        int row = tid >> 2, part = tid & 3;
        uint4 v = *(uint4*)&Ost[row * 40 + part * 8];
        *(uint4*)&attn_b[((size_t)(bp * S_ + q0 + row)) * 256 + hp * 32 + part * 8] = v;
    }
}

// ---------------- launch ----------------
extern "C" void kernel_launch(void* const* d_in, const int* in_sizes, int n_in,
                              void* d_out, int out_size, void* d_ws, size_t ws_size,
                              hipStream_t stream) {
    const float* x     = (const float*)d_in[0];
    const int*   adj   = (const int*)d_in[1];
    const float* w_qkv = (const float*)d_in[2];
    const float* b_qkv = (const float*)d_in[3];
    const float* ln_g  = (const float*)d_in[4];
    const float* ln_b  = (const float*)d_in[5];
    const float* w_fc  = (const float*)d_in[6];
    const float* b_fc  = (const float*)d_in[7];
    const float* w_z   = (const float*)d_in[8];
    const float* b_z   = (const float*)d_in[9];
    const float* u_z   = (const float*)d_in[10];
    const float* w_r   = (const float*)d_in[11];
    const float* u_r   = (const float*)d_in[12];
    const float* w_g   = (const float*)d_in[13];
    const float* u_g   = (const float*)d_in[14];
    float* out = (float*)d_out;

    const size_t TOK  = (size_t)B_ * S_;       // 8192
    const size_t TOKD = TOK * D_;              // 2,097,152
    ushort_t* xn_b   = (ushort_t*)d_ws;
    ushort_t* qkv_b  = xn_b + TOKD;            // TOK*768
    ushort_t* attn_b = qkv_b + TOK * 768;
    ushort_t* wb     = attn_b + TOKD;          // 655,360 elems (frag-ordered)
    uint_t*   bits   = (uint_t*)(wb + WQ_SZ + 7 * WS_SZ);   // 524,288 words (transposed layout)
    ushort_t* vTb    = (ushort_t*)(bits + (size_t)B_ * S_ * S_ / 32);  // 1024*2048

    ushort_t* wq_b  = wb;
    ushort_t* wfc_b = wb + WQ_SZ;
    ushort_t* wz_b  = wfc_b + WS_SZ;
    ushort_t* uz_b  = wz_b + WS_SZ;
    ushort_t* wr_b  = uz_b + WS_SZ;
    ushort_t* ur_b  = wr_b + WS_SZ;
    ushort_t* wg_b  = ur_b + WS_SZ;
    ushort_t* ug_b  = wg_b + WS_SZ;

    prep_kernel<<<NB_ADJ + NB_WC + NB_LN, 256, 0, stream>>>(
        adj, bits, w_qkv, w_fc, w_z, u_z, w_r, u_r, w_g, u_g, wb,
        x, ln_g, ln_b, xn_b);

    gemm_qkv<<<dim3(12, 128), 256, 0, stream>>>(xn_b, wq_b, b_qkv, qkv_b, vTb);

    attn_kernel<<<dim3(S_ / 64, B_ * H_), 256, 0, stream>>>(qkv_b, vTb, bits, attn_b);

    fused_gate<<<512, 512, 0, stream>>>(
        attn_b, x, wfc_b, wz_b, uz_b, wr_b, ur_b, wg_b, ug_b, b_fc, b_z, out);
}